// Round 2
// baseline (3956.140 us; speedup 1.0000x reference)
//
#include <hip/hip_runtime.h>

#define N_LAT 16384
#define N_EMB 16384
#define DIM   256
#define XQ_ELEMS (N_LAT * DIM)   // 4194304

// ---------------- workspace layout ----------------
// [0]      float  enorm[16384]    (64 KB)
// [65536]  u64    best[16384]     (128 KB)  init 0xFF
// [196608] int    hist[16384]     (64 KB)   init 0x00
// [262144] double bsum[16384]     (128 KB)  written unconditionally

// ---- Kernel A: embed row squared norms, fp64 accumulate for accuracy ----
__global__ __launch_bounds__(256) void k_enorm(const float* __restrict__ embed,
                                               float* __restrict__ enorm) {
    const int gid  = blockIdx.x * 256 + threadIdx.x;
    const int wave = gid >> 6;            // 1024 waves total (grid 256)
    const int lane = threadIdx.x & 63;
    for (int row = wave; row < N_EMB; row += 1024) {
        const float4 v = *reinterpret_cast<const float4*>(&embed[row * DIM + lane * 4]);
        double s = (double)v.x * v.x + (double)v.y * v.y +
                   (double)v.z * v.z + (double)v.w * v.w;
#pragma unroll
        for (int m = 32; m; m >>= 1) s += __shfl_xor(s, m, 64);
        if (lane == 0) enorm[row] = (float)s;
    }
}

// ---- Kernel B: fused fp32 GEMM + argmin over codes ----
// grid: (128 row-blocks, 16 code-chunks), 256 threads.
// Each block: 128 rows x 1024 codes, BK=32 over d=256.
// Staging mapping: r = wave*32 + (lane>>1) spans 32 banks -> 2-way (free)
// LDS write conflicts; lane pairs consume full 128B lines (coalesced).
// Register prefetch: next tile's global loads issue before compute.
__global__ __launch_bounds__(256, 3) void k_argmin(const float* __restrict__ x,
                                                   const float* __restrict__ embed,
                                                   const float* __restrict__ enorm,
                                                   unsigned long long* __restrict__ best) {
    __shared__ float As[32][128];   // transposed: As[k][row]
    __shared__ float Bs[32][128];   // transposed: Bs[k][col]

    const int tid  = threadIdx.x;
    const int row0 = blockIdx.x * 128;
    const int kc   = blockIdx.y;            // 0..15

    // staging coords: conflict-free writes (bank = sr mod 32, 2 lanes/bank)
    const int w   = tid >> 6;               // wave 0..3
    const int l   = tid & 63;
    const int sr  = w * 32 + (l >> 1);      // 0..127
    const int sc0 = l & 1;                  // c4 = sc0 + 2*j

    // compute coords
    const int tx = tid & 15, ty = tid >> 4;
    const int r_lo = ty * 4, r_hi = 64 + ty * 4;
    const int c_lo = tx * 4, c_hi = 64 + tx * 4;

    float rmin[8];
    int   ridx[8];
#pragma unroll
    for (int i = 0; i < 8; ++i) { rmin[i] = 3.402823e38f; ridx[i] = 0; }

    const float* xrow = x + (size_t)(row0 + sr) * DIM;
    const float* brow0 = embed + (size_t)(kc * 1024 + sr) * DIM;

    float4 pa[4], pb[4];
    auto LOAD = [&](int ct, int d0f) {
        const float* br = brow0 + (size_t)(ct * 128) * DIM;
#pragma unroll
        for (int j = 0; j < 4; ++j) {
            const int c4 = sc0 + 2 * j;
            pa[j] = *reinterpret_cast<const float4*>(&xrow[d0f + c4 * 4]);
            pb[j] = *reinterpret_cast<const float4*>(&br[d0f + c4 * 4]);
        }
    };

    LOAD(0, 0);

    for (int ct = 0; ct < 8; ++ct) {            // 8 code tiles of 128
        float acc[8][8];
#pragma unroll
        for (int i = 0; i < 8; ++i)
#pragma unroll
            for (int j = 0; j < 8; ++j) acc[i][j] = 0.0f;

        for (int d0s = 0; d0s < 8; ++d0s) {
            __syncthreads();                    // LDS free (all waves done reading)
#pragma unroll
            for (int j = 0; j < 4; ++j) {
                const int k0 = (sc0 + 2 * j) * 4;
                As[k0 + 0][sr] = pa[j].x; As[k0 + 1][sr] = pa[j].y;
                As[k0 + 2][sr] = pa[j].z; As[k0 + 3][sr] = pa[j].w;
                Bs[k0 + 0][sr] = pb[j].x; Bs[k0 + 1][sr] = pb[j].y;
                Bs[k0 + 2][sr] = pb[j].z; Bs[k0 + 3][sr] = pb[j].w;
            }
            __syncthreads();                    // LDS ready
            // issue next tile's loads; latency hides under the 2048 FMAs below
            {
                int nd = d0s + 1, nct = ct;
                if (nd == 8) { nd = 0; ++nct; }
                if (nct < 8) LOAD(nct, nd * 32);
            }
#pragma unroll
            for (int kk = 0; kk < 32; ++kk) {
                float a[8], b[8];
                *reinterpret_cast<float4*>(&a[0]) = *reinterpret_cast<const float4*>(&As[kk][r_lo]);
                *reinterpret_cast<float4*>(&a[4]) = *reinterpret_cast<const float4*>(&As[kk][r_hi]);
                *reinterpret_cast<float4*>(&b[0]) = *reinterpret_cast<const float4*>(&Bs[kk][c_lo]);
                *reinterpret_cast<float4*>(&b[4]) = *reinterpret_cast<const float4*>(&Bs[kk][c_hi]);
#pragma unroll
                for (int i = 0; i < 8; ++i)
#pragma unroll
                    for (int j = 0; j < 8; ++j)
                        acc[i][j] = fmaf(a[i], b[j], acc[i][j]);
            }
        }
        // epilogue: dist = ||e||^2 - 2*dot ; cols ascending -> first-min tie-break
        const int col0 = kc * 1024 + ct * 128;
#pragma unroll
        for (int j = 0; j < 8; ++j) {
            const int col = col0 + (j < 4 ? c_lo + j : c_hi + (j - 4));
            const float s = enorm[col];
#pragma unroll
            for (int i = 0; i < 8; ++i) {
                const float v = fmaf(-2.0f, acc[i][j], s);
                if (v < rmin[i]) { rmin[i] = v; ridx[i] = col; }
            }
        }
    }
    // reduce across the 16 tx lanes sharing each row, then one atomic per row
#pragma unroll
    for (int i = 0; i < 8; ++i) {
        unsigned u = __float_as_uint(rmin[i]);
        u = (u & 0x80000000u) ? ~u : (u | 0x80000000u);   // monotonic float->uint
        unsigned long long p = ((unsigned long long)u << 32) | (unsigned)ridx[i];
#pragma unroll
        for (int m = 1; m < 16; m <<= 1) {
            const unsigned long long q = __shfl_xor(p, m, 64);
            p = (q < p) ? q : p;
        }
        if (tx == 0) {
            const int row = row0 + (i < 4 ? r_lo + i : r_hi + (i - 4));
            atomicMin(&best[row], p);
        }
    }
}

// ---- Kernel C: gather x_q, STE output, per-block SSE, usage histogram, indices ----
__global__ __launch_bounds__(256) void k_gather(const float* __restrict__ x,
                                                const float* __restrict__ embed,
                                                const unsigned long long* __restrict__ best,
                                                float* __restrict__ out,
                                                int* __restrict__ hist,
                                                double* __restrict__ bsum) {
    __shared__ double partial[4];
    const int row = blockIdx.x;
    const int t   = threadIdx.x;
    const int idx = (int)(best[row] & 0xFFFFFFFFULL);
    const float e  = embed[(size_t)idx * DIM + t];
    const float xv = x[(size_t)row * DIM + t];
    const float d  = e - xv;                 // x_q - x (reference rounding)
    out[(size_t)row * DIM + t] = xv + d;     // x + (x_q - x): bitwise-matches STE
    double sq = (double)d * (double)d;
#pragma unroll
    for (int m = 32; m; m >>= 1) sq += __shfl_xor(sq, m, 64);
    const int lane = t & 63, wv = t >> 6;
    if (lane == 0) partial[wv] = sq;
    __syncthreads();
    if (t == 0) {
        bsum[row] = partial[0] + partial[1] + partial[2] + partial[3];
        atomicAdd(&hist[idx], 1);
        out[XQ_ELEMS + 2 + row] = (float)idx;   // embed_ind as float
    }
}

// ---- Kernel D: finalize scalars ----
__global__ __launch_bounds__(256) void k_final(const int* __restrict__ hist,
                                               const double* __restrict__ bsum,
                                               float* __restrict__ out) {
    __shared__ int    cpart[4];
    __shared__ double spart[4];
    const int t = threadIdx.x;
    int cnt = 0; double s = 0.0;
    for (int i = t; i < N_EMB; i += 256) {
        cnt += (hist[i] == 0) ? 1 : 0;
        s += bsum[i];
    }
#pragma unroll
    for (int m = 32; m; m >>= 1) {
        cnt += __shfl_xor(cnt, m, 64);
        s   += __shfl_xor(s, m, 64);
    }
    const int lane = t & 63, wv = t >> 6;
    if (lane == 0) { cpart[wv] = cnt; spart[wv] = s; }
    __syncthreads();
    if (t == 0) {
        const double sse = spart[0] + spart[1] + spart[2] + spart[3];
        out[XQ_ELEMS + 0] = (float)(1.25 * sse / (double)XQ_ELEMS);   // quant_loss
        out[XQ_ELEMS + 1] = (float)(cpart[0] + cpart[1] + cpart[2] + cpart[3]); // unused
    }
}

extern "C" void kernel_launch(void* const* d_in, const int* in_sizes, int n_in,
                              void* d_out, int out_size, void* d_ws, size_t ws_size,
                              hipStream_t stream) {
    const float* x     = (const float*)d_in[0];   // 128*128*256
    const float* embed = (const float*)d_in[1];   // 16384*256
    float* out = (float*)d_out;

    char* ws = (char*)d_ws;
    float*              enorm = (float*)(ws + 0);
    unsigned long long* best  = (unsigned long long*)(ws + 65536);
    int*                hist  = (int*)(ws + 196608);
    double*             bsum  = (double*)(ws + 262144);

    hipMemsetAsync(best, 0xFF, N_LAT * sizeof(unsigned long long), stream);
    hipMemsetAsync(hist, 0x00, N_EMB * sizeof(int), stream);

    k_enorm <<<256, 256, 0, stream>>>(embed, enorm);
    k_argmin<<<dim3(128, 16), 256, 0, stream>>>(x, embed, enorm, best);
    k_gather<<<N_LAT, 256, 0, stream>>>(x, embed, best, out, hist, bsum);
    k_final <<<1, 256, 0, stream>>>(hist, bsum, out);
}

// Round 5
// 525.175 us; speedup vs baseline: 7.5330x; 7.5330x over previous
//
#include <hip/hip_runtime.h>

#define N_LAT 16384
#define N_EMB 16384
#define DIM   256
#define XQ_ELEMS (N_LAT * DIM)   // 4194304

typedef __attribute__((ext_vector_type(8))) _Float16 f16x8;
typedef __attribute__((ext_vector_type(4))) float    f32x4;

// XOR swizzle on intra-tile byte address (8KB tile = [128 rows][64 bytes]):
// spreads the 16-row x 4-kgroup b128 fragment reads evenly over the 8 bank-quads.
#define SWZ(a) ((a) ^ ((((a) >> 6) & 7) << 4))

// async global->LDS, 16B per lane; LDS dest is wave-uniform base + lane*16
#define GLD16(g, l) __builtin_amdgcn_global_load_lds( \
    (const __attribute__((address_space(1))) unsigned int*)(g), \
    (__attribute__((address_space(3))) unsigned int*)(l), 16, 0, 0)

// ---------------- workspace layout ----------------
// [0]       float  enorm[16384]                (64 KB)
// [64K]     u64    best[16384]                 (128 KB) init 0xFF
// [192K]    int    hist[16384]                 (64 KB)  init 0
// [256K]    double bsum[16384]                 (128 KB)
// [384K]    f16    xhi_sw  (8 MB)  swizzled tile-major
// [384K+8M] f16    xlo_sw  (8 MB)
// [384K+16M]f16    ehi_sw  (8 MB)
// [384K+24M]f16    elo_sw  (8 MB)

// ---- split fp32 -> (hi, lo) fp16, stored in swizzled tile-major order ----
// dst byte = (rowblk*8 + kstep)*8192 + SWZ((row&127)*64 + (k8&3)*16)
__global__ __launch_bounds__(256) void k_convert(const float* __restrict__ src,
                                                 char* __restrict__ hi,
                                                 char* __restrict__ lo) {
    const int gid = blockIdx.x * 256 + threadIdx.x;  // 16384*32 threads, 8 elems each
    const int row = gid >> 5, k8 = gid & 31;
    const float* s = src + (size_t)row * DIM + k8 * 8;
    float f[8];
    *reinterpret_cast<float4*>(&f[0]) = *reinterpret_cast<const float4*>(s);
    *reinterpret_cast<float4*>(&f[4]) = *reinterpret_cast<const float4*>(s + 4);
    f16x8 hv, lv;
#pragma unroll
    for (int m = 0; m < 8; ++m) {
        const _Float16 h = (_Float16)f[m];
        hv[m] = h;
        lv[m] = (_Float16)(f[m] - (float)h);
    }
    const int dst = ((row >> 7) * 8 + (k8 >> 2)) * 8192 + SWZ((row & 127) * 64 + (k8 & 3) * 16);
    *reinterpret_cast<f16x8*>(hi + dst) = hv;
    *reinterpret_cast<f16x8*>(lo + dst) = lv;
}

// ---- embed row squared norms, fp64 accumulate (bitwise-proven vs ref) ----
__global__ __launch_bounds__(256) void k_enorm(const float* __restrict__ embed,
                                               float* __restrict__ enorm) {
    const int gid  = blockIdx.x * 256 + threadIdx.x;
    const int wave = gid >> 6;
    const int lane = threadIdx.x & 63;
    for (int row = wave; row < N_EMB; row += 1024) {
        const float4 v = *reinterpret_cast<const float4*>(&embed[row * DIM + lane * 4]);
        double s = (double)v.x * v.x + (double)v.y * v.y +
                   (double)v.z * v.z + (double)v.w * v.w;
#pragma unroll
        for (int m = 32; m; m >>= 1) s += __shfl_xor(s, m, 64);
        if (lane == 0) enorm[row] = (float)s;
    }
}

// ---- fused split-fp16 MFMA GEMM + argmin ----
// grid (128 rowblocks, 16 code chunks), 256 thr = 4 waves, wave tile 32x128.
// dist = ||e||^2 - 2*(xhi.ehi + xhi.elo + xlo.ehi)  (lo.lo ~1e-7, below fp32 noise)
__global__ __launch_bounds__(256) void k_argmin(const char* __restrict__ xhi,
                                                const char* __restrict__ xlo,
                                                const char* __restrict__ ehi,
                                                const char* __restrict__ elo,
                                                const float* __restrict__ enorm,
                                                unsigned long long* __restrict__ best) {
    __shared__ char smem[32768];
    char* As_hi = smem;
    char* As_lo = smem + 8192;
    char* Bs_hi = smem + 16384;
    char* Bs_lo = smem + 24576;

    const int tid = threadIdx.x;
    const int w   = tid >> 6;        // wave 0..3 -> rows w*32..+31
    const int l   = tid & 63;
    const int lg  = l >> 4;          // k-group / D-row-group
    const int lr  = l & 15;          // A-row / B-col / D-col within frag

    const int row0 = blockIdx.x * 128;
    const int kc   = blockIdx.y;     // 0..15

    const size_t abase = (size_t)blockIdx.x * 8 * 8192 + (size_t)w * 2048;
    const int    lo16  = l * 16;

    // swizzled fragment byte offsets (16B-aligned)
    int aoff[2];
#pragma unroll
    for (int i = 0; i < 2; ++i) {
        const int r = w * 32 + i * 16 + lr;
        aoff[i] = SWZ(r * 64 + lg * 16);
    }
    int boff[8];
#pragma unroll
    for (int j = 0; j < 8; ++j) {
        const int c = j * 16 + lr;
        boff[j] = SWZ(c * 64 + lg * 16);
    }

    unsigned long long pmin[2][4];
#pragma unroll
    for (int i = 0; i < 2; ++i)
#pragma unroll
        for (int t = 0; t < 4; ++t) pmin[i][t] = ~0ULL;

    for (int ct = 0; ct < 8; ++ct) {
        const int    cb    = kc * 8 + ct;                // code block 0..127
        const size_t bbase = (size_t)cb * 8 * 8192 + (size_t)w * 2048;

        f32x4 acc[2][8];
#pragma unroll
        for (int i = 0; i < 2; ++i)
#pragma unroll
            for (int j = 0; j < 8; ++j) acc[i][j] = (f32x4)0.0f;

        for (int ks = 0; ks < 8; ++ks) {
            __syncthreads();                 // all waves done reading LDS
#pragma unroll
            for (int q = 0; q < 2; ++q) {
                const int    o  = w * 2048 + q * 1024;
                const size_t ga = abase + (size_t)ks * 8192 + q * 1024 + lo16;
                const size_t gb = bbase + (size_t)ks * 8192 + q * 1024 + lo16;
                GLD16(xhi + ga, As_hi + o);
                GLD16(xlo + ga, As_lo + o);
                GLD16(ehi + gb, Bs_hi + o);
                GLD16(elo + gb, Bs_lo + o);
            }
            __syncthreads();                 // vmcnt(0) drained by compiler before barrier

            f16x8 ah[2], al[2];
#pragma unroll
            for (int i = 0; i < 2; ++i) {
                ah[i] = *reinterpret_cast<const f16x8*>(As_hi + aoff[i]);
                al[i] = *reinterpret_cast<const f16x8*>(As_lo + aoff[i]);
            }
#pragma unroll
            for (int j = 0; j < 8; ++j) {
                const f16x8 bh = *reinterpret_cast<const f16x8*>(Bs_hi + boff[j]);
                const f16x8 bl = *reinterpret_cast<const f16x8*>(Bs_lo + boff[j]);
#pragma unroll
                for (int i = 0; i < 2; ++i) {
                    acc[i][j] = __builtin_amdgcn_mfma_f32_16x16x32_f16(ah[i], bh, acc[i][j], 0, 0, 0);
                    acc[i][j] = __builtin_amdgcn_mfma_f32_16x16x32_f16(ah[i], bl, acc[i][j], 0, 0, 0);
                    acc[i][j] = __builtin_amdgcn_mfma_f32_16x16x32_f16(al[i], bh, acc[i][j], 0, 0, 0);
                }
            }
        }
        // epilogue: dist, running packed argmin (cols ascend -> first-min tie-break)
        const int colbase = kc * 1024 + ct * 128;
#pragma unroll
        for (int j = 0; j < 8; ++j) {
            const int   col = colbase + j * 16 + lr;
            const float s   = enorm[col];
#pragma unroll
            for (int i = 0; i < 2; ++i)
#pragma unroll
                for (int t = 0; t < 4; ++t) {
                    const float v = fmaf(-2.0f, acc[i][j][t], s);
                    unsigned u = __float_as_uint(v);
                    u = (u & 0x80000000u) ? ~u : (u | 0x80000000u);  // monotone map
                    const unsigned long long p = ((unsigned long long)u << 32) | (unsigned)col;
                    if (p < pmin[i][t]) pmin[i][t] = p;
                }
        }
    }
    // reduce over the 16 col-lanes of each group, one atomic per row
#pragma unroll
    for (int i = 0; i < 2; ++i)
#pragma unroll
        for (int t = 0; t < 4; ++t) {
            unsigned long long p = pmin[i][t];
#pragma unroll
            for (int m = 1; m < 16; m <<= 1) {
                const unsigned long long q = __shfl_xor(p, m, 64);
                if (q < p) p = q;
            }
            if (lr == 0) {
                const int row = row0 + w * 32 + i * 16 + lg * 4 + t;
                atomicMin(&best[row], p);
            }
        }
}

// ---- gather x_q, STE output, per-row SSE, histogram, indices ----
__global__ __launch_bounds__(256) void k_gather(const float* __restrict__ x,
                                                const float* __restrict__ embed,
                                                const unsigned long long* __restrict__ best,
                                                float* __restrict__ out,
                                                int* __restrict__ hist,
                                                double* __restrict__ bsum) {
    __shared__ double partial[4];
    const int row = blockIdx.x;
    const int t   = threadIdx.x;
    const int idx = (int)(best[row] & 0xFFFFFFFFULL);
    const float e  = embed[(size_t)idx * DIM + t];
    const float xv = x[(size_t)row * DIM + t];
    const float d  = e - xv;
    out[(size_t)row * DIM + t] = xv + d;
    double sq = (double)d * (double)d;
#pragma unroll
    for (int m = 32; m; m >>= 1) sq += __shfl_xor(sq, m, 64);
    const int lane = t & 63, wv = t >> 6;
    if (lane == 0) partial[wv] = sq;
    __syncthreads();
    if (t == 0) {
        bsum[row] = partial[0] + partial[1] + partial[2] + partial[3];
        atomicAdd(&hist[idx], 1);
        out[XQ_ELEMS + 2 + row] = (float)idx;
    }
}

__global__ __launch_bounds__(256) void k_final(const int* __restrict__ hist,
                                               const double* __restrict__ bsum,
                                               float* __restrict__ out) {
    __shared__ int    cpart[4];
    __shared__ double spart[4];
    const int t = threadIdx.x;
    int cnt = 0; double s = 0.0;
    for (int i = t; i < N_EMB; i += 256) {
        cnt += (hist[i] == 0) ? 1 : 0;
        s += bsum[i];
    }
#pragma unroll
    for (int m = 32; m; m >>= 1) {
        cnt += __shfl_xor(cnt, m, 64);
        s   += __shfl_xor(s, m, 64);
    }
    const int lane = t & 63, wv = t >> 6;
    if (lane == 0) { cpart[wv] = cnt; spart[wv] = s; }
    __syncthreads();
    if (t == 0) {
        const double sse = spart[0] + spart[1] + spart[2] + spart[3];
        out[XQ_ELEMS + 0] = (float)(1.25 * sse / (double)XQ_ELEMS);
        out[XQ_ELEMS + 1] = (float)(cpart[0] + cpart[1] + cpart[2] + cpart[3]);
    }
}

extern "C" void kernel_launch(void* const* d_in, const int* in_sizes, int n_in,
                              void* d_out, int out_size, void* d_ws, size_t ws_size,
                              hipStream_t stream) {
    const float* x     = (const float*)d_in[0];
    const float* embed = (const float*)d_in[1];
    float* out = (float*)d_out;

    char* ws = (char*)d_ws;
    float*              enorm = (float*)(ws + 0);
    unsigned long long* best  = (unsigned long long*)(ws + 65536);
    int*                hist  = (int*)(ws + 196608);
    double*             bsum  = (double*)(ws + 262144);
    char*               xhi   = ws + 393216;
    char*               xlo   = xhi + 8388608;
    char*               ehi   = xlo + 8388608;
    char*               elo   = ehi + 8388608;

    hipMemsetAsync(best, 0xFF, N_LAT * sizeof(unsigned long long), stream);
    hipMemsetAsync(hist, 0x00, N_EMB * sizeof(int), stream);

    k_convert<<<2048, 256, 0, stream>>>(x, xhi, xlo);
    k_convert<<<2048, 256, 0, stream>>>(embed, ehi, elo);
    k_enorm  <<<256, 256, 0, stream>>>(embed, enorm);
    k_argmin <<<dim3(128, 16), 256, 0, stream>>>(xhi, xlo, ehi, elo, enorm, best);
    k_gather <<<N_LAT, 256, 0, stream>>>(x, embed, best, out, hist, bsum);
    k_final  <<<1, 256, 0, stream>>>(hist, bsum, out);
}